// Round 2
// baseline (849.993 us; speedup 1.0000x reference)
//
#include <hip/hip_runtime.h>

// QNet forward, MI355X. Round 2: fp32 inputs/outputs (per reference dtypes),
// correctness-first VALU implementation. h intermediate stored bf16 in d_ws
// (32MB, proven safe in round 1).
// Shapes: B=8192, A=32, N_OBS=128, H1=128, HX=64, N_ACT=16.
// gates/Wg/bg are dead code in the reference -> skipped.

#define NB   8192
#define NA   32
#define NOBS 128
#define NH1  128
#define HXX  64
#define NACT 16

__device__ __forceinline__ float bflo(unsigned u){ return __uint_as_float(u << 16); }
__device__ __forceinline__ float bfhi(unsigned u){ return __uint_as_float(u & 0xFFFF0000u); }
__device__ __forceinline__ float bf2f(unsigned short s){ return __uint_as_float(((unsigned)s) << 16); }
__device__ __forceinline__ unsigned short f2bf(float f){
    unsigned u = __float_as_uint(f);
    u += 0x7FFFu + ((u >> 16) & 1u);      // round-to-nearest-even
    return (unsigned short)(u >> 16);
}
__device__ __forceinline__ void unpack8(uint4 v, float f[8]){
    f[0]=bflo(v.x); f[1]=bfhi(v.x);
    f[2]=bflo(v.y); f[3]=bfhi(v.y);
    f[4]=bflo(v.z); f[5]=bfhi(v.z);
    f[6]=bflo(v.w); f[7]=bfhi(v.w);
}

// ---------------------------------------------------------------------------
// Encoder: x = relu(obs @ W1 + b1); h = relu(x @ W2 + b2) -> ws (bf16)
// grid (B/256, A), block 256. One thread = one batch row of one agent.
// W2 (32KB fp32) fully in LDS; W1 staged in 4 chunks of 16KB (output-column
// chunks of 32). All LDS reads are wave-uniform broadcasts (conflict-free).
// ---------------------------------------------------------------------------
extern "C" __global__ __launch_bounds__(256)
void enc_kernel(const float* __restrict__ obs,
                const float* __restrict__ W1,
                const float* __restrict__ b1,
                const float* __restrict__ W2,
                const float* __restrict__ b2,
                unsigned short* __restrict__ hws)
{
    __shared__ float w2s[NH1 * HXX];   // 32KB, [i][c]
    __shared__ float w1c[NH1 * 32];    // 16KB, [k][c-chunk]
    __shared__ float b1s[NH1];
    __shared__ float b2s[HXX];

    const int t = threadIdx.x;
    const int a = blockIdx.y;

    {   // stage W2 (8192 floats = 2048 float4, coalesced)
        const float4* g2 = (const float4*)(W2 + (size_t)a * NH1 * HXX);
        float4* l2 = (float4*)w2s;
        #pragma unroll
        for (int i = 0; i < 8; ++i) l2[t + 256 * i] = g2[t + 256 * i];
        if (t < NH1) b1s[t] = b1[a * NH1 + t];
        if (t < HXX) b2s[t] = b2[a * HXX + t];
    }
    __syncthreads();

    const int b = blockIdx.x * 256 + t;
    const float4* orow = (const float4*)(obs + ((size_t)b * NA + a) * NOBS);
    const float*  W1g  = W1 + (size_t)a * NOBS * NH1;

    float hacc[HXX];
    #pragma unroll
    for (int c = 0; c < HXX; ++c) hacc[c] = b2s[c];

    for (int ic = 0; ic < 4; ++ic) {
        __syncthreads();   // previous chunk's readers done before overwrite
        // stage W1 columns [ic*32, ic*32+32) for all 128 k rows: 4096 floats
        #pragma unroll
        for (int r = 0; r < 16; ++r) {
            int l = t + 256 * r;                       // l = k*32 + c
            w1c[l] = W1g[(l >> 5) * NH1 + ic * 32 + (l & 31)];
        }
        __syncthreads();

        float x[32];
        #pragma unroll
        for (int i = 0; i < 32; ++i) x[i] = b1s[ic * 32 + i];

        for (int k4 = 0; k4 < 32; ++k4) {              // obs re-read: L1/L2 hit
            float4 of = orow[k4];
            float ofv[4] = {of.x, of.y, of.z, of.w};
            #pragma unroll
            for (int j = 0; j < 4; ++j) {
                const float4* wr = (const float4*)(w1c + (k4 * 4 + j) * 32);
                #pragma unroll
                for (int q = 0; q < 8; ++q) {
                    float4 w = wr[q];                  // ds_read_b128 broadcast
                    x[q * 4 + 0] += ofv[j] * w.x;
                    x[q * 4 + 1] += ofv[j] * w.y;
                    x[q * 4 + 2] += ofv[j] * w.z;
                    x[q * 4 + 3] += ofv[j] * w.w;
                }
            }
        }
        #pragma unroll
        for (int i = 0; i < 32; ++i) {
            float xv = fmaxf(x[i], 0.0f);              // relu
            const float4* wr = (const float4*)(w2s + (ic * 32 + i) * HXX);
            #pragma unroll
            for (int q = 0; q < 16; ++q) {
                float4 w = wr[q];
                hacc[q * 4 + 0] += xv * w.x;
                hacc[q * 4 + 1] += xv * w.y;
                hacc[q * 4 + 2] += xv * w.z;
                hacc[q * 4 + 3] += xv * w.w;
            }
        }
    }

    // relu, pack to bf16, store h[b][a][0..63]
    unsigned* hrow = (unsigned*)(hws + ((size_t)b * NA + a) * HXX);
    #pragma unroll
    for (int c2 = 0; c2 < 32; ++c2) {
        float lo = fmaxf(hacc[2 * c2],     0.0f);
        float hi = fmaxf(hacc[2 * c2 + 1], 0.0f);
        hrow[c2] = (unsigned)f2bf(lo) | ((unsigned)f2bf(hi) << 16);
    }
}

// ---------------------------------------------------------------------------
// Decoder: comm = masked-mean_j(h[b,j]); h2 = tanh([h|comm] @ Wc + bc);
//          q = h2 @ Wd + bd   (fp32 weights, fp32 out; h tile bf16 in LDS)
// grid (B/8), block 256. Thread t: agent i = t>>3, local row bl = t&7.
// ---------------------------------------------------------------------------
extern "C" __global__ __launch_bounds__(256)
void dec_kernel(const unsigned short* __restrict__ hws,
                const int*            __restrict__ cmask,
                const float* __restrict__ Wc,
                const float* __restrict__ bc,
                const float* __restrict__ Wd,
                const float* __restrict__ bd,
                float*       __restrict__ out)
{
    __shared__ uint4 hl4[8 * 257];   // 8 slabs of 256 uint4 (+1 pad) ~32KB

    const int t  = threadIdx.x;
    const int b0 = blockIdx.x * 8;

    {   // stage h tile: 8 rows x 32 agents x 64 bf16 = 2048 uint4, coalesced
        const uint4* g = (const uint4*)(hws + (size_t)b0 * NA * HXX);
        #pragma unroll
        for (int it = 0; it < 8; ++it) {
            int c   = t + 256 * it;
            int bl  = c >> 8;
            int rem = c & 255;
            hl4[bl * 257 + rem] = g[c];
        }
    }
    __syncthreads();

    const int i  = t >> 3;   // agent
    const int bl = t & 7;    // local batch row

    // ---- comm: sum over j != i with mask, then / max(count,1)
    float comm[HXX];
    #pragma unroll
    for (int c = 0; c < HXX; ++c) comm[c] = 0.0f;
    int cnt = 0;
    for (int j = 0; j < NA; ++j) {
        int m = (j == i) ? 0 : cmask[i * NA + j];
        cnt += m;
        float mf = (float)m;
        const uint4* hr = &hl4[bl * 257 + j * 8];
        #pragma unroll
        for (int c8 = 0; c8 < 8; ++c8) {
            float hf[8];
            unpack8(hr[c8], hf);
            #pragma unroll
            for (int mm = 0; mm < 8; ++mm) comm[c8 * 8 + mm] += mf * hf[mm];
        }
    }
    const float rinv = 1.0f / fmaxf((float)cnt, 1.0f);
    #pragma unroll
    for (int c = 0; c < HXX; ++c) comm[c] *= rinv;

    // ---- h2 = tanh(hown @ Wc[0:64] + comm @ Wc[64:128] + bc)
    float acc[HXX];
    {
        const float4* bcr = (const float4*)(bc + i * HXX);
        #pragma unroll
        for (int q = 0; q < 16; ++q) {
            float4 bv = bcr[q];
            acc[q * 4 + 0] = bv.x; acc[q * 4 + 1] = bv.y;
            acc[q * 4 + 2] = bv.z; acc[q * 4 + 3] = bv.w;
        }
    }
    const unsigned short* hown = (const unsigned short*)&hl4[bl * 257 + i * 8];
    for (int k = 0; k < HXX; ++k) {
        float hv = bf2f(hown[k]);
        const float4* wr = (const float4*)(Wc + ((size_t)i * 128 + k) * HXX);
        #pragma unroll
        for (int q = 0; q < 16; ++q) {
            float4 w = wr[q];
            acc[q * 4 + 0] += hv * w.x; acc[q * 4 + 1] += hv * w.y;
            acc[q * 4 + 2] += hv * w.z; acc[q * 4 + 3] += hv * w.w;
        }
    }
    for (int k = 0; k < HXX; ++k) {
        float cv = comm[k];
        const float4* wr = (const float4*)(Wc + ((size_t)i * 128 + 64 + k) * HXX);
        #pragma unroll
        for (int q = 0; q < 16; ++q) {
            float4 w = wr[q];
            acc[q * 4 + 0] += cv * w.x; acc[q * 4 + 1] += cv * w.y;
            acc[q * 4 + 2] += cv * w.z; acc[q * 4 + 3] += cv * w.w;
        }
    }
    #pragma unroll
    for (int c = 0; c < HXX; ++c) acc[c] = tanhf(acc[c]);

    // ---- q = h2 @ Wd + bd
    float qv[NACT];
    {
        const float4* bdr = (const float4*)(bd + i * NACT);
        #pragma unroll
        for (int q = 0; q < 4; ++q) {
            float4 bv = bdr[q];
            qv[q * 4 + 0] = bv.x; qv[q * 4 + 1] = bv.y;
            qv[q * 4 + 2] = bv.z; qv[q * 4 + 3] = bv.w;
        }
    }
    for (int k = 0; k < HXX; ++k) {
        float hv = acc[k];
        const float4* wr = (const float4*)(Wd + ((size_t)i * HXX + k) * NACT);
        #pragma unroll
        for (int q = 0; q < 4; ++q) {
            float4 w = wr[q];
            qv[q * 4 + 0] += hv * w.x; qv[q * 4 + 1] += hv * w.y;
            qv[q * 4 + 2] += hv * w.z; qv[q * 4 + 3] += hv * w.w;
        }
    }

    // ---- store q[b][i][0..15] fp32 (4 float4, contiguous 64B)
    float4* o4 = (float4*)(out + ((size_t)(b0 + bl) * NA + i) * NACT);
    #pragma unroll
    for (int q = 0; q < 4; ++q)
        o4[q] = make_float4(qv[q * 4 + 0], qv[q * 4 + 1], qv[q * 4 + 2], qv[q * 4 + 3]);
}

// ---------------------------------------------------------------------------
extern "C" void kernel_launch(void* const* d_in, const int* in_sizes, int n_in,
                              void* d_out, int out_size, void* d_ws, size_t ws_size,
                              hipStream_t stream)
{
    const float* obs = (const float*)d_in[0];
    const float* W1  = (const float*)d_in[1];
    const float* b1  = (const float*)d_in[2];
    const float* W2  = (const float*)d_in[3];
    const float* b2  = (const float*)d_in[4];
    // d_in[5] = Wg, d_in[6] = bg : gates are dead code in the reference output
    const float* Wc  = (const float*)d_in[7];
    const float* bc  = (const float*)d_in[8];
    const float* Wd  = (const float*)d_in[9];
    const float* bd  = (const float*)d_in[10];
    const int*   cm  = (const int*)d_in[11];

    float*          outp = (float*)d_out;
    unsigned short* hws  = (unsigned short*)d_ws;   // h: [B][A][64] bf16 = 32MB

    hipLaunchKernelGGL(enc_kernel, dim3(NB / 256, NA), dim3(256), 0, stream,
                       obs, W1, b1, W2, b2, hws);
    hipLaunchKernelGGL(dec_kernel, dim3(NB / 8), dim3(256), 0, stream,
                       hws, cm, Wc, bc, Wd, bd, outp);
}

// Round 4
// 326.650 us; speedup vs baseline: 2.6022x; 2.6022x over previous
//
#include <hip/hip_runtime.h>

// QNet forward, MI355X. Round 4: MFMA f16 for all GEMMs; fixes round-3's
// dec h-tile staging indexing bug (4096 uint4, 256/row, 8/agent).
// B=8192, A=32, NOBS=128, NH1=128, HX=64, NACT=16. fp32 in/out.
// gates/Wg/bg dead code -> skipped.
//
// ws layout (halfs): h[B][A][64] | W1pack | W2pack | Wcpack | Wdpack  (35.7MB)
// Packed B-fragment layout for mfma_f32_16x16x32_f16:
//   frag(a, nt, s)[lane*8 + j] = W[a][s*32 + (lane>>4)*8 + j][nt*16 + (lane&15)]
// A-operand: lane holds A[m=lane&15][k=(lane>>4)*8+j]; C/D: col=lane&15,
// row=(lane>>4)*4+reg  (per guide, m89-verified layout).

#define NB   8192
#define NA   32
#define NOBS 128
#define NH1  128
#define HXX  64
#define NACT 16

typedef _Float16 half8  __attribute__((ext_vector_type(8)));
typedef _Float16 half2v __attribute__((ext_vector_type(2)));
typedef float    floatx4 __attribute__((ext_vector_type(4)));

#define MFMA16(af, bf, c) __builtin_amdgcn_mfma_f32_16x16x32_f16((af), (bf), (c), 0, 0, 0)

// ws offsets in halfs
#define HWS_OFF 0
#define W1P_OFF (NB * NA * HXX)                    // 16,777,216
#define W1P_CNT (NA * 8 * 4 * 512)                 // 524,288
#define W2P_OFF (W1P_OFF + W1P_CNT)
#define W2P_CNT (NA * 4 * 4 * 512)                 // 262,144
#define WCP_OFF (W2P_OFF + W2P_CNT)
#define WCP_CNT (NA * 4 * 4 * 512)                 // 262,144
#define WDP_OFF (WCP_OFF + WCP_CNT)
#define WDP_CNT (NA * 1 * 2 * 512)                 // 32,768

#define DEC_LDS (512 * 136 * 2 + 32 * 32 * 4 + 32 * 4)   // 143,488 B

// ---------------------------------------------------------------------------
// Pack a (A, K, N) fp32 weight into f16 MFMA B-fragments.
// ---------------------------------------------------------------------------
extern "C" __global__ void pack_kernel(const float* __restrict__ src,
                                       _Float16* __restrict__ dst,
                                       int K, int N, int NT, int NS, int total)
{
    int e = blockIdx.x * 256 + threadIdx.x;
    if (e >= total) return;
    int j = e & 7, l = (e >> 3) & 63;
    int rest = e >> 9;
    int s  = rest % NS; rest /= NS;
    int nt = rest % NT; rest /= NT;
    int a  = rest;
    int k = s * 32 + (l >> 4) * 8 + j;
    int n = nt * 16 + (l & 15);
    dst[e] = (_Float16)src[((size_t)a * K + k) * N + n];
}

// ---------------------------------------------------------------------------
// Encoder: h = relu(relu(obs@W1+b1)@W2+b2) -> ws (f16)
// grid (64, 32), block 256 (4 waves). M=128, K=128, N=128 then N=64.
// Wave w stages and computes rows 32w..32w+31 only (wave-private).
// ---------------------------------------------------------------------------
extern "C" __global__ __launch_bounds__(256)
void enc_kernel(const float* __restrict__ obs,
                const float* __restrict__ b1,
                const float* __restrict__ b2,
                const _Float16* __restrict__ W1p,
                const _Float16* __restrict__ W2p,
                _Float16* __restrict__ hws)
{
    __shared__ _Float16 A[128 * 136];   // 34.8 KB, pad 8 halfs/row

    const int t  = threadIdx.x;
    const int a  = blockIdx.y;
    const int b0 = blockIdx.x * 128;

    {   // stage obs fp32 -> f16 LDS (2 threads per row)
        const int r = t >> 1, hh = t & 1;
        const float4* src = (const float4*)(obs + ((size_t)(b0 + r) * NA + a) * NOBS) + hh * 16;
        _Float16* dst = A + r * 136 + hh * 64;
        #pragma unroll
        for (int q = 0; q < 16; ++q) {
            float4 g = src[q];
            dst[q * 4 + 0] = (_Float16)g.x; dst[q * 4 + 1] = (_Float16)g.y;
            dst[q * 4 + 2] = (_Float16)g.z; dst[q * 4 + 3] = (_Float16)g.w;
        }
    }
    const int w = t >> 6, l = t & 63, lm = l & 15, lq = l >> 4;

    float b1v[8], b2v[4];
    #pragma unroll
    for (int nt = 0; nt < 8; ++nt) b1v[nt] = b1[a * NH1 + nt * 16 + lm];
    #pragma unroll
    for (int nt = 0; nt < 4; ++nt) b2v[nt] = b2[a * HXX + nt * 16 + lm];

    __syncthreads();

    // ---- GEMM1: x = obs @ W1   (wave w: m-tiles 2w, 2w+1; 8 n-tiles)
    floatx4 acc[2][8];
    #pragma unroll
    for (int mt = 0; mt < 2; ++mt)
        #pragma unroll
        for (int nt = 0; nt < 8; ++nt) acc[mt][nt] = (floatx4){0.f, 0.f, 0.f, 0.f};

    for (int s = 0; s < 4; ++s) {
        half8 af[2];
        #pragma unroll
        for (int mt = 0; mt < 2; ++mt)
            af[mt] = *(const half8*)&A[(w * 32 + mt * 16 + lm) * 136 + s * 32 + lq * 8];
        #pragma unroll
        for (int nt = 0; nt < 8; ++nt) {
            half8 bf = *(const half8*)&W1p[(((a * 8 + nt) * 4 + s) * 512) + l * 8];
            acc[0][nt] = MFMA16(af[0], bf, acc[0][nt]);
            acc[1][nt] = MFMA16(af[1], bf, acc[1][nt]);
        }
    }

    // relu + write X back into A (wave-private rows -> no barrier)
    #pragma unroll
    for (int mt = 0; mt < 2; ++mt)
        #pragma unroll
        for (int nt = 0; nt < 8; ++nt)
            #pragma unroll
            for (int v = 0; v < 4; ++v) {
                float x = fmaxf(acc[mt][nt][v] + b1v[nt], 0.f);
                A[(w * 32 + mt * 16 + lq * 4 + v) * 136 + nt * 16 + lm] = (_Float16)x;
            }

    // ---- GEMM2: h = X @ W2  (4 n-tiles)
    floatx4 acc2[2][4];
    #pragma unroll
    for (int mt = 0; mt < 2; ++mt)
        #pragma unroll
        for (int nt = 0; nt < 4; ++nt) acc2[mt][nt] = (floatx4){0.f, 0.f, 0.f, 0.f};

    for (int s = 0; s < 4; ++s) {
        half8 af[2];
        #pragma unroll
        for (int mt = 0; mt < 2; ++mt)
            af[mt] = *(const half8*)&A[(w * 32 + mt * 16 + lm) * 136 + s * 32 + lq * 8];
        #pragma unroll
        for (int nt = 0; nt < 4; ++nt) {
            half8 bf = *(const half8*)&W2p[(((a * 4 + nt) * 4 + s) * 512) + l * 8];
            acc2[0][nt] = MFMA16(af[0], bf, acc2[0][nt]);
            acc2[1][nt] = MFMA16(af[1], bf, acc2[1][nt]);
        }
    }

    // relu + store h (f16) to ws
    #pragma unroll
    for (int mt = 0; mt < 2; ++mt)
        #pragma unroll
        for (int nt = 0; nt < 4; ++nt)
            #pragma unroll
            for (int v = 0; v < 4; ++v) {
                float x = fmaxf(acc2[mt][nt][v] + b2v[nt], 0.f);
                int row = w * 32 + mt * 16 + lq * 4 + v;
                hws[((size_t)(b0 + row) * NA + a) * HXX + nt * 16 + lm] = (_Float16)x;
            }
}

// ---------------------------------------------------------------------------
// Decoder: comm (masked mean over agents) + tanh([h|comm]@Wc+bc) @ Wd + bd.
// grid 512, block 512 (8 waves). Block = 16 batch rows x all 32 agents.
// A2 (LDS, 512x136 f16): rows = agent*16+r; left half h, right half comm.
// Wave w owns agents 4w..4w+3 (m-tiles). After Wc GEMM, h2 reuses A2 (stride 72).
// ---------------------------------------------------------------------------
extern "C" __global__ __launch_bounds__(512)
void dec_kernel(const _Float16* __restrict__ hws,
                const int* __restrict__ cmask,
                const float* __restrict__ bc,
                const float* __restrict__ bd,
                const _Float16* __restrict__ Wcp,
                const _Float16* __restrict__ Wdp,
                float* __restrict__ out)
{
    extern __shared__ char smem[];
    _Float16* A  = (_Float16*)smem;                 // 512*136
    float*    Mn = (float*)(smem + 512 * 136 * 2);  // 32*32
    int*      cnt = (int*)(Mn + 32 * 32);           // 32

    const int t  = threadIdx.x;
    const int b0 = blockIdx.x * 16;

    {   // stage h tile: 16 rows x 32 agents x 64 f16 = 4096 uint4, coalesced
        // row = 256 uint4, agent = 8 uint4  (round-3 bug was 512/16 here)
        const uint4* src = (const uint4*)(hws + (size_t)b0 * NA * HXX);
        #pragma unroll
        for (int it = 0; it < 8; ++it) {
            int idx = it * 512 + t;
            int r = idx >> 8, rem = idx & 255;
            int i = rem >> 3, c8 = rem & 7;
            *(uint4*)&A[(i * 16 + r) * 136 + c8 * 8] = src[idx];
        }
    }
    if (t < NA) {   // comm counts (diag excluded)
        int c = 0;
        for (int j = 0; j < NA; ++j) c += (j != t && cmask[t * NA + j]) ? 1 : 0;
        cnt[t] = c;
    }
    __syncthreads();

    for (int e = t; e < NA * NA; e += 512) {   // normalized mask
        int i = e >> 5, j = e & 31;
        float v = 0.f;
        if (j != i && cmask[i * NA + j]) {
            int c = cnt[i]; v = 1.0f / (float)(c > 1 ? c : 1);
        }
        Mn[e] = v;
    }
    __syncthreads();

    {   // comm: thread (r = t>>5, cw = t&31) does channels 2cw,2cw+1, all agents
        const int r = t >> 5, cw = t & 31;
        float h0[32], h1[32];
        #pragma unroll
        for (int j = 0; j < 32; ++j) {
            half2v hp = *(const half2v*)&A[(j * 16 + r) * 136 + cw * 2];
            h0[j] = (float)hp[0]; h1[j] = (float)hp[1];
        }
        for (int i = 0; i < 32; ++i) {
            const float4* mr = (const float4*)&Mn[i * 32];
            float a0 = 0.f, a1 = 0.f;
            #pragma unroll
            for (int j4 = 0; j4 < 8; ++j4) {
                float4 m = mr[j4];
                a0 += m.x * h0[j4*4+0] + m.y * h0[j4*4+1] + m.z * h0[j4*4+2] + m.w * h0[j4*4+3];
                a1 += m.x * h1[j4*4+0] + m.y * h1[j4*4+1] + m.z * h1[j4*4+2] + m.w * h1[j4*4+3];
            }
            half2v o; o[0] = (_Float16)a0; o[1] = (_Float16)a1;
            *(half2v*)&A[(i * 16 + r) * 136 + 64 + cw * 2] = o;
        }
    }
    __syncthreads();

    const int w = t >> 6, l = t & 63, lm = l & 15, lq = l >> 4;

    // ---- Wc GEMM: M=512 (32 m-tiles = agents), K=128, N=64
    floatx4 acc[4][4];
    #pragma unroll
    for (int g = 0; g < 4; ++g)
        #pragma unroll
        for (int nt = 0; nt < 4; ++nt) acc[g][nt] = (floatx4){0.f, 0.f, 0.f, 0.f};

    for (int s = 0; s < 4; ++s) {
        #pragma unroll
        for (int g = 0; g < 4; ++g) {
            int ag = w * 4 + g;
            half8 af = *(const half8*)&A[(ag * 16 + lm) * 136 + s * 32 + lq * 8];
            #pragma unroll
            for (int nt = 0; nt < 4; ++nt) {
                half8 bf = *(const half8*)&Wcp[(((ag * 4 + nt) * 4 + s) * 512) + l * 8];
                acc[g][nt] = MFMA16(af, bf, acc[g][nt]);
            }
        }
    }
    __syncthreads();   // all A2 reads done before h2 overwrites the buffer

    // tanh epilogue -> h2 (f16) into A, stride 72
    #pragma unroll
    for (int g = 0; g < 4; ++g) {
        int ag = w * 4 + g;
        #pragma unroll
        for (int nt = 0; nt < 4; ++nt) {
            float bcv = bc[ag * HXX + nt * 16 + lm];
            #pragma unroll
            for (int v = 0; v < 4; ++v) {
                float x = tanhf(acc[g][nt][v] + bcv);
                A[(ag * 16 + lq * 4 + v) * 72 + nt * 16 + lm] = (_Float16)x;
            }
        }
    }
    // wave reads only its own agents' h2 rows -> no barrier needed

    // ---- Wd GEMM: K=64, N=16
    floatx4 acc3[4];
    #pragma unroll
    for (int g = 0; g < 4; ++g) acc3[g] = (floatx4){0.f, 0.f, 0.f, 0.f};

    for (int s = 0; s < 2; ++s) {
        #pragma unroll
        for (int g = 0; g < 4; ++g) {
            int ag = w * 4 + g;
            half8 af = *(const half8*)&A[(ag * 16 + lm) * 72 + s * 32 + lq * 8];
            half8 bf = *(const half8*)&Wdp[((ag * 2 + s) * 512) + l * 8];
            acc3[g] = MFMA16(af, bf, acc3[g]);
        }
    }

    #pragma unroll
    for (int g = 0; g < 4; ++g) {
        int ag = w * 4 + g;
        float bdv = bd[ag * NACT + lm];
        #pragma unroll
        for (int v = 0; v < 4; ++v) {
            int row = lq * 4 + v;
            out[((size_t)(b0 + row) * NA + ag) * NACT + lm] = acc3[g][v] + bdv;
        }
    }
}

// ---------------------------------------------------------------------------
extern "C" void kernel_launch(void* const* d_in, const int* in_sizes, int n_in,
                              void* d_out, int out_size, void* d_ws, size_t ws_size,
                              hipStream_t stream)
{
    const float* obs = (const float*)d_in[0];
    const float* W1  = (const float*)d_in[1];
    const float* b1  = (const float*)d_in[2];
    const float* W2  = (const float*)d_in[3];
    const float* b2  = (const float*)d_in[4];
    const float* Wc  = (const float*)d_in[7];
    const float* bc  = (const float*)d_in[8];
    const float* Wd  = (const float*)d_in[9];
    const float* bd  = (const float*)d_in[10];
    const int*   cm  = (const int*)d_in[11];

    float*    outp = (float*)d_out;
    _Float16* ws   = (_Float16*)d_ws;

    _Float16* hws = ws + HWS_OFF;
    _Float16* W1p = ws + W1P_OFF;
    _Float16* W2p = ws + W2P_OFF;
    _Float16* Wcp = ws + WCP_OFF;
    _Float16* Wdp = ws + WDP_OFF;

    hipLaunchKernelGGL(pack_kernel, dim3(W1P_CNT / 256), dim3(256), 0, stream,
                       W1, W1p, 128, 128, 8, 4, W1P_CNT);
    hipLaunchKernelGGL(pack_kernel, dim3(W2P_CNT / 256), dim3(256), 0, stream,
                       W2, W2p, 128, 64, 4, 4, W2P_CNT);
    hipLaunchKernelGGL(pack_kernel, dim3(WCP_CNT / 256), dim3(256), 0, stream,
                       Wc, Wcp, 128, 64, 4, 4, WCP_CNT);
    hipLaunchKernelGGL(pack_kernel, dim3(WDP_CNT / 256), dim3(256), 0, stream,
                       Wd, Wdp, 64, 16, 1, 2, WDP_CNT);

    hipLaunchKernelGGL(enc_kernel, dim3(NB / 128, NA), dim3(256), 0, stream,
                       obs, b1, b2, W1p, W2p, hws);

    (void)hipFuncSetAttribute((const void*)dec_kernel,
                              hipFuncAttributeMaxDynamicSharedMemorySize, DEC_LDS);
    hipLaunchKernelGGL(dec_kernel, dim3(NB / 16), dim3(512), DEC_LDS, stream,
                       hws, cm, bc, bd, Wcp, Wdp, outp);
}